// Round 1
// baseline (533.011 us; speedup 1.0000x reference)
//
#include <hip/hip_runtime.h>

// VectorQuantizer: z [16,4096,256] f32, embedding [1024,256] f32
// out (f32, flat): z_q[16777216] | vq_loss[1] | commitment_loss[1] | idxs-as-float[65536]

#define ROWS 65536
#define EDIM 256
#define NEMB 1024
#define NTOT 16777216

#define OUT_VQ  16777216
#define OUT_CM  16777217
#define OUT_IDX 16777218

#define BM 128
#define BN 128
#define BK 16
#define LSTR 20   // LDS row stride in floats: mult of 4 (b128 align), 20*4B -> 4-bank rotation per row

// ---------------- e2: per-code squared norm ----------------
__global__ __launch_bounds__(256) void e2_kernel(const float* __restrict__ emb,
                                                 float* __restrict__ e2) {
  int c = blockIdx.x * 256 + threadIdx.x;   // 1024 total
  const float4* p = (const float4*)(emb + (size_t)c * EDIM);
  float s = 0.f;
  #pragma unroll 8
  for (int j = 0; j < EDIM / 4; ++j) {
    float4 v = p[j];
    s += v.x * v.x; s += v.y * v.y; s += v.z * v.z; s += v.w * v.w;
  }
  e2[c] = s;
}

// ---------------- argmax over similarity ----------------
// similarity = ||z||^2 + ||e||^2 - 2 z.e ; reference uses argmax (farthest code).
__global__ __launch_bounds__(256) void argmax_kernel(
    const float* __restrict__ z, const float* __restrict__ emb,
    const float* __restrict__ e2, int* __restrict__ idx_out,
    float* __restrict__ idxf_out) {
  __shared__ float As[BM * LSTR];   // 10240 B, rows x 16k (row-major, stride 20)
  __shared__ float Bs[BN * LSTR];   // 10240 B, codes x 16k
  __shared__ float Z2[BM];

  const int tid = threadIdx.x;
  const int tx = tid & 15;          // code lane group
  const int ty = tid >> 4;          // row lane group (0..15)
  const int row0 = blockIdx.x * BM;
  const float4* z4 = (const float4*)z;

  float bestv[8];
  int   besti[8];
  #pragma unroll
  for (int m = 0; m < 8; ++m) { bestv[m] = -3.402823466e+38f; besti[m] = 0; }

  // per-row ||z||^2 (sequential over k, matches ref rounding regime closely)
  if (tid < BM) {
    const float4* p = z4 + (size_t)(row0 + tid) * (EDIM / 4);
    float s = 0.f;
    #pragma unroll 8
    for (int j = 0; j < EDIM / 4; ++j) {
      float4 v = p[j];
      s += v.x * v.x; s += v.y * v.y; s += v.z * v.z; s += v.w * v.w;
    }
    Z2[tid] = s;
  }
  __syncthreads();
  float z2r[8];
  #pragma unroll
  for (int m = 0; m < 8; ++m) z2r[m] = Z2[ty + 16 * m];

  for (int nc = 0; nc < NEMB; nc += BN) {
    float dot[8][8];
    #pragma unroll
    for (int m = 0; m < 8; ++m)
      #pragma unroll
      for (int n = 0; n < 8; ++n) dot[m][n] = 0.f;

    for (int kb = 0; kb < EDIM; kb += BK) {
      __syncthreads();
      // stage A (128 rows x 16 k) and B (128 codes x 16 k), float4 coalesced
      #pragma unroll
      for (int i = 0; i < 2; ++i) {
        int f = tid + 256 * i;        // 0..511
        int r = f >> 2;               // 0..127
        int c4 = f & 3;               // 0..3 (k quad)
        float4 va = z4[(size_t)(row0 + r) * (EDIM / 4) + (kb >> 2) + c4];
        *(float4*)&As[r * LSTR + 4 * c4] = va;
        float4 vb = *(const float4*)&emb[(size_t)(nc + r) * EDIM + kb + 4 * c4];
        *(float4*)&Bs[r * LSTR + 4 * c4] = vb;
      }
      __syncthreads();
      // 16 k-steps: dot-product micro-kernel, b128 along k
      #pragma unroll
      for (int g = 0; g < 4; ++g) {
        float4 b4[8];
        #pragma unroll
        for (int n = 0; n < 8; ++n)
          b4[n] = *(const float4*)&Bs[(tx + 16 * n) * LSTR + 4 * g];
        #pragma unroll
        for (int m = 0; m < 8; ++m) {
          float4 a = *(const float4*)&As[(ty + 16 * m) * LSTR + 4 * g];
          #pragma unroll
          for (int n = 0; n < 8; ++n) {
            dot[m][n] = fmaf(a.x, b4[n].x, dot[m][n]);
            dot[m][n] = fmaf(a.y, b4[n].y, dot[m][n]);
            dot[m][n] = fmaf(a.z, b4[n].z, dot[m][n]);
            dot[m][n] = fmaf(a.w, b4[n].w, dot[m][n]);
          }
        }
      }
    }

    // compare: s = (z2 + e2) - 2*dot  (2*dot exact -> fmaf matches ref rounding)
    #pragma unroll
    for (int n = 0; n < 8; ++n) {
      int c = nc + tx + 16 * n;
      float e2v = e2[c];
      #pragma unroll
      for (int m = 0; m < 8; ++m) {
        float t = z2r[m] + e2v;
        float s = fmaf(dot[m][n], -2.0f, t);
        if (s > bestv[m] || (s == bestv[m] && c < besti[m])) { bestv[m] = s; besti[m] = c; }
      }
    }
  }

  // cross-thread reduce per row (16 tx candidates), idx-aware tie-break
  __syncthreads();
  float* RedV = As;            // reuse LDS (128*17*4 = 8704 B <= 10240)
  int*   RedI = (int*)Bs;
  #pragma unroll
  for (int m = 0; m < 8; ++m) {
    int r = ty + 16 * m;
    RedV[r * 17 + tx] = bestv[m];
    RedI[r * 17 + tx] = besti[m];
  }
  __syncthreads();
  if (tid < BM) {
    float bv = RedV[tid * 17 + 0];
    int bi = RedI[tid * 17 + 0];
    #pragma unroll
    for (int j = 1; j < 16; ++j) {
      float v = RedV[tid * 17 + j];
      int i2 = RedI[tid * 17 + j];
      if (v > bv || (v == bv && i2 < bi)) { bv = v; bi = i2; }
    }
    idx_out[row0 + tid] = bi;
    idxf_out[row0 + tid] = (float)bi;
  }
}

// ---------------- gather z_q + squared-diff partial sums ----------------
__global__ __launch_bounds__(256) void gather_kernel(
    const float* __restrict__ z, const float* __restrict__ emb,
    const int* __restrict__ idxs, float* __restrict__ out,
    float* __restrict__ partials) {
  const int tid = threadIdx.x;
  const int b = blockIdx.x;            // 1024 blocks, 64 rows each
  const float4* z4 = (const float4*)z;
  float4* q4 = (float4*)out;
  float acc = 0.f;
  #pragma unroll
  for (int i = 0; i < 16; ++i) {
    int f = b * 4096 + tid + 256 * i;  // float4 index
    int row = f >> 6;
    int c4 = f & 63;
    int e = idxs[row];                 // wave-uniform -> scalar broadcast
    float4 ev = *(const float4*)&emb[(size_t)e * EDIM + 4 * c4];
    float4 zv = z4[f];
    q4[f] = ev;
    float dx = ev.x - zv.x, dy = ev.y - zv.y, dz = ev.z - zv.z, dw = ev.w - zv.w;
    acc += dx * dx + dy * dy + dz * dz + dw * dw;
  }
  __shared__ float red[256];
  red[tid] = acc;
  __syncthreads();
  #pragma unroll
  for (int sN = 128; sN > 0; sN >>= 1) {
    if (tid < sN) red[tid] += red[tid + sN];
    __syncthreads();
  }
  if (tid == 0) partials[b] = red[0];
}

// ---------------- deterministic final reduce ----------------
__global__ void finalize_kernel(const float* __restrict__ partials,
                                float* __restrict__ out) {
  if (threadIdx.x == 0 && blockIdx.x == 0) {
    double s = 0.0;
    for (int i = 0; i < 1024; ++i) s += (double)partials[i];
    float m = (float)(s / 16777216.0);
    out[OUT_VQ] = m;
    out[OUT_CM] = 0.25f * m;
  }
}

extern "C" void kernel_launch(void* const* d_in, const int* in_sizes, int n_in,
                              void* d_out, int out_size, void* d_ws, size_t ws_size,
                              hipStream_t stream) {
  const float* z   = (const float*)d_in[0];
  const float* emb = (const float*)d_in[1];
  float* out = (float*)d_out;

  // workspace: e2[1024] | idxs[65536] (int) | partials[1024]  (~270 KB)
  float* e2       = (float*)d_ws;
  int*   idxs     = (int*)((char*)d_ws + 4096);
  float* partials = (float*)((char*)d_ws + 4096 + 262144);

  e2_kernel<<<NEMB / 256, 256, 0, stream>>>(emb, e2);
  argmax_kernel<<<ROWS / BM, 256, 0, stream>>>(z, emb, e2, idxs, out + OUT_IDX);
  gather_kernel<<<1024, 256, 0, stream>>>(z, emb, idxs, out, partials);
  finalize_kernel<<<1, 64, 0, stream>>>(partials, out);
}